// Round 6
// baseline (145.927 us; speedup 1.0000x reference)
//
#include <hip/hip_runtime.h>
#include <math.h>

// TeacherMLP fused forward.
// R6 change vs R5 (model: single issue port, v_exp_f32 = 16 cyc/wave64
// quarter-rate, 60% of issue cycles):
//   SOFTWARE exp2 on the full-rate pipe: 2^t = ldexp(poly5(f), rint(t)),
//   f in [-0.5,0.5], poly = Taylor in ln2 (rel err 2.4e-6). Cost/elem:
//   rint(2)+pk_sub(1)+cvt(2)+5 pk_fma(5)+ldexp(2) = 12 cyc vs 16 HW trans.
//   Per-iter issue 426 -> ~346 => predict mlp 50.9 -> ~41us.
//   Clamp raised 32->48 (den <= 2^109 < 2^127 still safe).
// Keep from R5: row-packed v2f math, merge-8 rcp (only 2 HW trans left per
// 16 elems), 512-thr blocks + split-K=2.

typedef float v2f __attribute__((ext_vector_type(2)));

#define SC   2.885390081777927f      /* 2*log2(e): exp2(SC*z) = e^{2z} */
#define INV  (1.0f / 2.885390081777927f)
#define INV2PI 0.15915494309189535f
#define HS_CLAMP 48.0f               /* clamp on SC-prescaled activations */
#define C8   0.00390625f             /* 2^-8 */

/* 2^f Taylor coefficients (powers of ln2 / k!) */
#define E0c 1.0f
#define E1c 0.6931471805599453f
#define E2c 0.24022650695910072f
#define E3c 0.05550410866482158f
#define E4c 0.009618129107628477f
#define E5c 0.0013333558146428443f

__device__ __forceinline__ float fast_rcp(float x)  { return __builtin_amdgcn_rcpf(x); }
__device__ __forceinline__ float fast_exp2(float x) { return __builtin_amdgcn_exp2f(x); }
__device__ __forceinline__ v2f pk2(float a, float b) { v2f r; r.x = a; r.y = b; return r; }

// software exp2 of both halves, entirely on the full-rate pipe.
// valid for t in ~[-64, 60]; rel err ~2.4e-6.
__device__ __forceinline__ v2f pk_exp2(v2f t) {
    float r0 = __builtin_rintf(t.x);        // v_rndne_f32 (full rate)
    float r1 = __builtin_rintf(t.y);
    v2f f = t - pk2(r0, r1);                // pk_add(neg), f in [-0.5,0.5]
    v2f p = pk2(E5c, E5c);
    p = p * f + E4c;                        // v_pk_fma_f32 chain
    p = p * f + E3c;
    p = p * f + E2c;
    p = p * f + E1c;
    p = p * f + E0c;
    int i0 = (int)r0, i1 = (int)r1;         // v_cvt_i32_f32
    return pk2(ldexpf(p.x, i0), ldexpf(p.y, i1));  // v_ldexp_f32
}

__global__ void weff_kernel(const float* __restrict__ W0, const int* __restrict__ I0,
                            const float* __restrict__ W1, const int* __restrict__ I1,
                            const float* __restrict__ W2, const int* __restrict__ I2,
                            float* __restrict__ ws) {
    int tid = blockIdx.x * blockDim.x + threadIdx.x;   // 0 .. 163839
    const float* W; const int* I; float* out; int outd; int e;
    if (tid < 65536)        { W = W0; I = I0; out = ws;          outd = 256; e = tid; }
    else if (tid < 131072)  { W = W1; I = I1; out = ws + 65536;  outd = 256; e = tid - 65536; }
    else if (tid < 163840)  { W = W2; I = I2; out = ws + 131072; outd = 128; e = tid - 131072; }
    else return;
    int o = e >> 8;       // out index (in-dim always 256)
    int i = e & 255;      // in index
    float w = W[e];       // coalesced (e = o*256 + i)
    int idx = I[e];
    // branchless atoms: [id, sin, tanh, square]
    float sn = __builtin_amdgcn_sinf(w * INV2PI);
    float th = 1.0f - 2.0f * fast_rcp(fast_exp2(w * SC) + 1.0f);
    float sq = w * w;
    float v = (idx == 1) ? sn : (idx == 2) ? th : (idx == 3) ? sq : w;
    // packed store: [i/4][o][i%4] -> main loop reads float4 of 4 K-values
    out[(i >> 2) * (outd * 4) + o * 4 + (i & 3)] = v;
}

// num/den of sum_{k=0..3} 1/B_k over 4 elements, both rows packed.
// B = exp2(t-8) + 2^-8 = 2^-8 * (e^{2z}+1); shift folds into the t-fma.
struct ND { v2f n, d; };
__device__ __forceinline__ ND tree4(float4 pa, float4 pb, float4 w) {
    v2f h0 = pk2(pa.x, pa.y), h1 = pk2(pa.z, pa.w);
    v2f h2 = pk2(pb.x, pb.y), h3 = pk2(pb.z, pb.w);
    v2f t0 = h0 * w.x - 8.0f, t1 = h1 * w.y - 8.0f;   // v_pk_fma
    v2f t2 = h2 * w.z - 8.0f, t3 = h3 * w.w - 8.0f;
    v2f B0 = pk_exp2(t0) + C8;
    v2f B1 = pk_exp2(t1) + C8;
    v2f B2 = pk_exp2(t2) + C8;
    v2f B3 = pk_exp2(t3) + C8;
    v2f S1 = B0 + B1, P1 = B0 * B1;
    v2f S2 = B2 + B3, P2 = B2 * B3;
    ND r; r.n = S1 * P2 + S2 * P1; r.d = P1 * P2; return r;
}

// merge two 4-trees: sum of 8 reciprocal terms with ONE rcp per row.
__device__ __forceinline__ v2f sig8(ND a, ND b) {
    v2f num = a.n * b.d + b.n * a.d;
    v2f den = a.d * b.d;
    v2f rd  = pk2(fast_rcp(den.x), fast_rcp(den.y));
    return num * rd;
}

__global__ __launch_bounds__(512, 8) void mlp_kernel(
    const float* __restrict__ x,  const float* __restrict__ b0,
    const float* __restrict__ b1, const float* __restrict__ b2,
    const float* __restrict__ ws, float* __restrict__ out) {
    const float4* We0 = (const float4*)ws;             // [64][256] packed [ic][o][4]
    const float4* We1 = (const float4*)(ws + 65536);   // [64][256]
    const float4* We2 = (const float4*)(ws + 131072);  // [64][128]

    __shared__ __align__(16) v2f hA[256];       // [i] = (row0_i, row1_i), SC-prescaled
    __shared__ __align__(16) v2f hB[256];
    __shared__ __align__(16) v2f part[512];     // split-K partials

    const int t = threadIdx.x;     // 0..511
    const int g = t >> 8;          // K-group (wave-uniform: waves 0-3 vs 4-7)
    const int o = t & 255;         // neuron
    const int row0 = blockIdx.x * 2;

    // stage 2 input rows, prescale + clamp (clamp is a no-op for real data)
    {
        float xv = x[(row0 + g) * 256 + o] * SC;
        xv = fminf(fmaxf(xv, -HS_CLAMP), HS_CLAMP);
        ((float*)(hA + o))[g] = xv;
    }
    __syncthreads();

    // ---------------- layer 0: hA -> hB ----------------
    {
        v2f acc = pk2(0.f, 0.f);
#pragma unroll 2
        for (int icc = 0; icc < 32; icc += 2) {
            int ic = g * 32 + icc;
            float4 w0 = We0[ic * 256 + o];
            float4 w1 = We0[(ic + 1) * 256 + o];
            const float4* hp = (const float4*)(hA + ic * 4);  // uniform addr -> broadcast
            ND r0 = tree4(hp[0], hp[1], w0);
            ND r1 = tree4(hp[2], hp[3], w1);
            acc += sig8(r0, r1);
        }
        part[g * 256 + o] = acc;
        __syncthreads();
        // combine: this thread produces h for (row g, neuron o)
        float s = ((const float*)(part + o))[g] + ((const float*)(part + 256 + o))[g];
        float h = (256.0f - 0.0078125f * s + b0[o]) * SC;   // 2^-7 undoes B-scale x2
        h = fminf(fmaxf(h, -HS_CLAMP), HS_CLAMP);
        ((float*)(hB + o))[g] = h;
        __syncthreads();
    }

    // ---------------- layer 1: hB -> hA ----------------
    {
        v2f acc = pk2(0.f, 0.f);
#pragma unroll 2
        for (int icc = 0; icc < 32; icc += 2) {
            int ic = g * 32 + icc;
            float4 w0 = We1[ic * 256 + o];
            float4 w1 = We1[(ic + 1) * 256 + o];
            const float4* hp = (const float4*)(hB + ic * 4);
            ND r0 = tree4(hp[0], hp[1], w0);
            ND r1 = tree4(hp[2], hp[3], w1);
            acc += sig8(r0, r1);
        }
        part[g * 256 + o] = acc;
        __syncthreads();
        float s = ((const float*)(part + o))[g] + ((const float*)(part + 256 + o))[g];
        float h = (256.0f - 0.0078125f * s + b1[o]) * SC;
        h = fminf(fmaxf(h, -HS_CLAMP), HS_CLAMP);
        ((float*)(hA + o))[g] = h;
        __syncthreads();
    }

    // ---------------- layer 2: hA -> out (identity matmul, 4-way split-K) --
    {
        const int o2 = t & 127;
        const int q  = t >> 7;     // K-quarter
        v2f acc = pk2(0.f, 0.f);
#pragma unroll 4
        for (int icc = 0; icc < 16; icc++) {
            int ic = q * 16 + icc;
            float4 w = We2[ic * 128 + o2];
            const float4* hp = (const float4*)(hA + ic * 4);
            float4 pa = hp[0], pb = hp[1];
            v2f h0 = pk2(pa.x, pa.y), h1 = pk2(pa.z, pa.w);
            v2f h2 = pk2(pb.x, pb.y), h3 = pk2(pb.z, pb.w);
            acc += h0 * w.x + h1 * w.y;   // v_pk_fma chain
            acc += h2 * w.z + h3 * w.w;
        }
        part[q * 128 + o2] = acc;
        __syncthreads();
        if (t < 256) {
            int r = t >> 7, oo = t & 127;
            float s = ((const float*)(part + oo))[r]
                    + ((const float*)(part + 128 + oo))[r]
                    + ((const float*)(part + 256 + oo))[r]
                    + ((const float*)(part + 384 + oo))[r];
            out[(row0 + r) * 128 + oo] = s * INV + b2[oo];  // undo SC prescale
        }
    }
}

extern "C" void kernel_launch(void* const* d_in, const int* in_sizes, int n_in,
                              void* d_out, int out_size, void* d_ws, size_t ws_size,
                              hipStream_t stream) {
    const float* x  = (const float*)d_in[0];
    const float* W0 = (const float*)d_in[1];
    const float* b0 = (const float*)d_in[2];
    const int*   I0 = (const int*)  d_in[3];
    const float* W1 = (const float*)d_in[4];
    const float* b1 = (const float*)d_in[5];
    const int*   I1 = (const int*)  d_in[6];
    const float* W2 = (const float*)d_in[7];
    const float* b2 = (const float*)d_in[8];
    const int*   I2 = (const int*)  d_in[9];
    float* ws  = (float*)d_ws;    // 163840 floats = 655360 B
    float* out = (float*)d_out;

    weff_kernel<<<640, 256, 0, stream>>>(W0, I0, W1, I1, W2, I2, ws);
    mlp_kernel<<<1024, 512, 0, stream>>>(x, b0, b1, b2, ws, out);
}

// Round 8
// 115.354 us; speedup vs baseline: 1.2650x; 1.2650x over previous
//
#include <hip/hip_runtime.h>
#include <math.h>

// TeacherMLP fused forward.
// R8 = R7 with the asm fixed: VOP3P packed-f32 sources must be 64-bit VGPR
// PAIRS. Scalar-broadcast is done with op_sel/op_sel_hi on a pair operand:
//   lo-broadcast: op_sel_hi:[1,0,1]          (both result halves read src1.lo)
//   hi-broadcast: op_sel:[0,1,0] op_sel_hi:[1,1,1] (both read src1.hi)
// Weight float4 is sliced into two v2f pairs (sub-register alias, no movs).
// Model (R5/R6 refit: compiler scalarizes v2f; HW exp2 ~8cyc quarter-rate;
// full-rate scalar ops ~55% of issue): pairing halves the full-rate slots,
// 334 -> ~233 cyc/iter => predict mlp 50.9 -> ~37us.

typedef float v2f __attribute__((ext_vector_type(2)));

#define SC   2.885390081777927f      /* 2*log2(e): exp2(SC*z) = e^{2z} */
#define INV  (1.0f / 2.885390081777927f)
#define INV2PI 0.15915494309189535f
#define HS_CLAMP 32.0f               /* clamp on SC-prescaled activations */
#define C8   0.00390625f             /* 2^-8 */

__device__ __forceinline__ float fast_rcp(float x)  { return __builtin_amdgcn_rcpf(x); }
__device__ __forceinline__ float fast_exp2(float x) { return __builtin_amdgcn_exp2f(x); }
__device__ __forceinline__ v2f pk2(float a, float b) { v2f r; r.x = a; r.y = b; return r; }

// ---- hand-emitted VOP3P packed-f32 (compiler scalarizes <2 x float> ops) ----
__device__ __forceinline__ v2f pk_add(v2f a, v2f b) {
    v2f d; asm("v_pk_add_f32 %0, %1, %2" : "=v"(d) : "v"(a), "v"(b)); return d;
}
__device__ __forceinline__ v2f pk_mul(v2f a, v2f b) {
    v2f d; asm("v_pk_mul_f32 %0, %1, %2" : "=v"(d) : "v"(a), "v"(b)); return d;
}
__device__ __forceinline__ v2f pk_fma(v2f a, v2f b, v2f c) {
    v2f d; asm("v_pk_fma_f32 %0, %1, %2, %3" : "=v"(d) : "v"(a), "v"(b), "v"(c)); return d;
}
// d = a * broadcast(src1.lo) + c
__device__ __forceinline__ v2f pk_fma_lo(v2f a, v2f s, v2f c) {
    v2f d; asm("v_pk_fma_f32 %0, %1, %2, %3 op_sel_hi:[1,0,1]"
               : "=v"(d) : "v"(a), "v"(s), "v"(c)); return d;
}
// d = a * broadcast(src1.hi) + c
__device__ __forceinline__ v2f pk_fma_hi(v2f a, v2f s, v2f c) {
    v2f d; asm("v_pk_fma_f32 %0, %1, %2, %3 op_sel:[0,1,0] op_sel_hi:[1,1,1]"
               : "=v"(d) : "v"(a), "v"(s), "v"(c)); return d;
}
__device__ __forceinline__ v2f pk_exp(v2f t) {  // 2 HW exp2 into a pair
    v2f e; e.x = fast_exp2(t.x); e.y = fast_exp2(t.y); return e;
}
__device__ __forceinline__ v2f lo2(float4 w) { return pk2(w.x, w.y); }
__device__ __forceinline__ v2f hi2(float4 w) { return pk2(w.z, w.w); }

__global__ void weff_kernel(const float* __restrict__ W0, const int* __restrict__ I0,
                            const float* __restrict__ W1, const int* __restrict__ I1,
                            const float* __restrict__ W2, const int* __restrict__ I2,
                            float* __restrict__ ws) {
    int tid = blockIdx.x * blockDim.x + threadIdx.x;   // 0 .. 163839
    const float* W; const int* I; float* out; int outd; int e;
    if (tid < 65536)        { W = W0; I = I0; out = ws;          outd = 256; e = tid; }
    else if (tid < 131072)  { W = W1; I = I1; out = ws + 65536;  outd = 256; e = tid - 65536; }
    else if (tid < 163840)  { W = W2; I = I2; out = ws + 131072; outd = 128; e = tid - 131072; }
    else return;
    int o = e >> 8;       // out index (in-dim always 256)
    int i = e & 255;      // in index
    float w = W[e];       // coalesced (e = o*256 + i)
    int idx = I[e];
    // branchless atoms: [id, sin, tanh, square]
    float sn = __builtin_amdgcn_sinf(w * INV2PI);
    float th = 1.0f - 2.0f * fast_rcp(fast_exp2(w * SC) + 1.0f);
    float sq = w * w;
    float v = (idx == 1) ? sn : (idx == 2) ? th : (idx == 3) ? sq : w;
    // packed store: [i/4][o][i%4] -> main loop reads float4 of 4 K-values
    out[(i >> 2) * (outd * 4) + o * 4 + (i & 3)] = v;
}

// num/den of sum_{k=0..3} 1/B_k over 4 i-values, both rows packed.
// B = exp2(t-8) + 2^-8 = 2^-8 * (e^{2z}+1); shift folds into the t-fma.
struct ND { v2f n, d; };
__device__ __forceinline__ ND tree4(float4 pa, float4 pb, float4 w, v2f m8, v2f c8) {
    v2f h0 = pk2(pa.x, pa.y), h1 = pk2(pa.z, pa.w);
    v2f h2 = pk2(pb.x, pb.y), h3 = pk2(pb.z, pb.w);
    v2f wxy = lo2(w), wzw = hi2(w);
    v2f B0 = pk_add(pk_exp(pk_fma_lo(h0, wxy, m8)), c8);
    v2f B1 = pk_add(pk_exp(pk_fma_hi(h1, wxy, m8)), c8);
    v2f B2 = pk_add(pk_exp(pk_fma_lo(h2, wzw, m8)), c8);
    v2f B3 = pk_add(pk_exp(pk_fma_hi(h3, wzw, m8)), c8);
    v2f S1 = pk_add(B0, B1), P1 = pk_mul(B0, B1);
    v2f S2 = pk_add(B2, B3), P2 = pk_mul(B2, B3);
    ND r;
    r.n = pk_fma(S2, P1, pk_mul(S1, P2));
    r.d = pk_mul(P1, P2);
    return r;
}

// merge two 4-trees (16 sigma-terms total, both rows) with ONE rcp per row.
__device__ __forceinline__ v2f sig8_acc(ND a, ND b, v2f acc) {
    v2f num = pk_fma(b.n, a.d, pk_mul(a.n, b.d));
    v2f den = pk_mul(a.d, b.d);
    v2f rd;  rd.x = fast_rcp(den.x); rd.y = fast_rcp(den.y);
    return pk_fma(num, rd, acc);
}

__global__ __launch_bounds__(512, 8) void mlp_kernel(
    const float* __restrict__ x,  const float* __restrict__ b0,
    const float* __restrict__ b1, const float* __restrict__ b2,
    const float* __restrict__ ws, float* __restrict__ out) {
    const float4* We0 = (const float4*)ws;             // [64][256] packed [ic][o][4]
    const float4* We1 = (const float4*)(ws + 65536);   // [64][256]
    const float4* We2 = (const float4*)(ws + 131072);  // [64][128]

    __shared__ __align__(16) v2f hA[256];       // [i] = (row0_i, row1_i), SC-prescaled
    __shared__ __align__(16) v2f hB[256];
    __shared__ __align__(16) v2f part[512];     // split-K partials

    const int t = threadIdx.x;     // 0..511
    const int g = t >> 8;          // K-group (wave-uniform: waves 0-3 vs 4-7)
    const int o = t & 255;         // neuron
    const int row0 = blockIdx.x * 2;

    const v2f m8 = pk2(-8.0f, -8.0f);
    const v2f c8 = pk2(C8, C8);

    // stage 2 input rows, prescale + clamp (clamp is a no-op for real data)
    {
        float xv = x[(row0 + g) * 256 + o] * SC;
        xv = fminf(fmaxf(xv, -HS_CLAMP), HS_CLAMP);
        ((float*)(hA + o))[g] = xv;
    }
    __syncthreads();

    // ---------------- layer 0: hA -> hB ----------------
    {
        v2f acc = pk2(0.f, 0.f);
#pragma unroll 2
        for (int icc = 0; icc < 32; icc += 2) {
            int ic = g * 32 + icc;
            float4 w0 = We0[ic * 256 + o];
            float4 w1 = We0[(ic + 1) * 256 + o];
            const float4* hp = (const float4*)(hA + ic * 4);  // uniform addr -> broadcast
            ND r0 = tree4(hp[0], hp[1], w0, m8, c8);
            ND r1 = tree4(hp[2], hp[3], w1, m8, c8);
            acc = sig8_acc(r0, r1, acc);
        }
        part[g * 256 + o] = acc;
        __syncthreads();
        // combine: this thread produces h for (row g, neuron o)
        float s = ((const float*)(part + o))[g] + ((const float*)(part + 256 + o))[g];
        float h = (256.0f - 0.0078125f * s + b0[o]) * SC;   // 2^-7 undoes B-scale x2
        h = fminf(fmaxf(h, -HS_CLAMP), HS_CLAMP);
        ((float*)(hB + o))[g] = h;
        __syncthreads();
    }

    // ---------------- layer 1: hB -> hA ----------------
    {
        v2f acc = pk2(0.f, 0.f);
#pragma unroll 2
        for (int icc = 0; icc < 32; icc += 2) {
            int ic = g * 32 + icc;
            float4 w0 = We1[ic * 256 + o];
            float4 w1 = We1[(ic + 1) * 256 + o];
            const float4* hp = (const float4*)(hB + ic * 4);
            ND r0 = tree4(hp[0], hp[1], w0, m8, c8);
            ND r1 = tree4(hp[2], hp[3], w1, m8, c8);
            acc = sig8_acc(r0, r1, acc);
        }
        part[g * 256 + o] = acc;
        __syncthreads();
        float s = ((const float*)(part + o))[g] + ((const float*)(part + 256 + o))[g];
        float h = (256.0f - 0.0078125f * s + b1[o]) * SC;
        h = fminf(fmaxf(h, -HS_CLAMP), HS_CLAMP);
        ((float*)(hA + o))[g] = h;
        __syncthreads();
    }

    // ---------------- layer 2: hA -> out (identity matmul, 4-way split-K) --
    {
        const int o2 = t & 127;
        const int q  = t >> 7;     // K-quarter
        v2f acc = pk2(0.f, 0.f);
#pragma unroll 4
        for (int icc = 0; icc < 16; icc++) {
            int ic = q * 16 + icc;
            float4 w = We2[ic * 128 + o2];
            const float4* hp = (const float4*)(hA + ic * 4);
            float4 pa = hp[0], pb = hp[1];
            v2f h0 = pk2(pa.x, pa.y), h1 = pk2(pa.z, pa.w);
            v2f h2 = pk2(pb.x, pb.y), h3 = pk2(pb.z, pb.w);
            v2f wxy = lo2(w), wzw = hi2(w);
            acc = pk_fma_lo(h0, wxy, acc);
            acc = pk_fma_hi(h1, wxy, acc);
            acc = pk_fma_lo(h2, wzw, acc);
            acc = pk_fma_hi(h3, wzw, acc);
        }
        part[q * 128 + o2] = acc;
        __syncthreads();
        if (t < 256) {
            int r = t >> 7, oo = t & 127;
            float s = ((const float*)(part + oo))[r]
                    + ((const float*)(part + 128 + oo))[r]
                    + ((const float*)(part + 256 + oo))[r]
                    + ((const float*)(part + 384 + oo))[r];
            out[(row0 + r) * 128 + oo] = s * INV + b2[oo];  // undo SC prescale
        }
    }
}

extern "C" void kernel_launch(void* const* d_in, const int* in_sizes, int n_in,
                              void* d_out, int out_size, void* d_ws, size_t ws_size,
                              hipStream_t stream) {
    const float* x  = (const float*)d_in[0];
    const float* W0 = (const float*)d_in[1];
    const float* b0 = (const float*)d_in[2];
    const int*   I0 = (const int*)  d_in[3];
    const float* W1 = (const float*)d_in[4];
    const float* b1 = (const float*)d_in[5];
    const int*   I1 = (const int*)  d_in[6];
    const float* W2 = (const float*)d_in[7];
    const float* b2 = (const float*)d_in[8];
    const int*   I2 = (const int*)  d_in[9];
    float* ws  = (float*)d_ws;    // 163840 floats = 655360 B
    float* out = (float*)d_out;

    weff_kernel<<<640, 256, 0, stream>>>(W0, I0, W1, I1, W2, I2, ws);
    mlp_kernel<<<1024, 512, 0, stream>>>(x, b0, b1, b2, ws, out);
}

// Round 10
// 113.209 us; speedup vs baseline: 1.2890x; 1.0189x over previous
//
#include <hip/hip_runtime.h>
#include <math.h>

// TeacherMLP fused forward.
// R10 = R9's intent (4 rows/thread as two independent packed pairs: halve
// weight loads, 2x ILP per wave) rebuilt as a MINIMAL diff of R8's passing
// code. R9 failed correctness (absmax 48); its logic diffs clean vs R8, so
// the suspects were (a) 2D-shared-array function params, (b) prefetch
// rotation under unroll+asm pressure, (c) launch_bounds(512,8) 64-VGPR spill
// corner. All three removed here: no helper fn, flat 1-D LDS arrays, no
// prefetch, launch_bounds(512,4).
// Decisive experiment: latency model -> ~40-44us; phantom-trans model
// (trans cycles uncounted in VALUBusy, R8 already issue-saturated) -> ~50us.

typedef float v2f __attribute__((ext_vector_type(2)));

#define SC   2.885390081777927f      /* 2*log2(e): exp2(SC*z) = e^{2z} */
#define INV  (1.0f / 2.885390081777927f)
#define INV2PI 0.15915494309189535f
#define HS_CLAMP 32.0f               /* clamp on SC-prescaled activations */
#define C8   0.00390625f             /* 2^-8 */

__device__ __forceinline__ float fast_rcp(float x)  { return __builtin_amdgcn_rcpf(x); }
__device__ __forceinline__ float fast_exp2(float x) { return __builtin_amdgcn_exp2f(x); }
__device__ __forceinline__ v2f pk2(float a, float b) { v2f r; r.x = a; r.y = b; return r; }

// ---- hand-emitted VOP3P packed-f32 (compiler scalarizes <2 x float> ops) ----
__device__ __forceinline__ v2f pk_add(v2f a, v2f b) {
    v2f d; asm("v_pk_add_f32 %0, %1, %2" : "=v"(d) : "v"(a), "v"(b)); return d;
}
__device__ __forceinline__ v2f pk_mul(v2f a, v2f b) {
    v2f d; asm("v_pk_mul_f32 %0, %1, %2" : "=v"(d) : "v"(a), "v"(b)); return d;
}
__device__ __forceinline__ v2f pk_fma(v2f a, v2f b, v2f c) {
    v2f d; asm("v_pk_fma_f32 %0, %1, %2, %3" : "=v"(d) : "v"(a), "v"(b), "v"(c)); return d;
}
// d = a * broadcast(src1.lo) + c
__device__ __forceinline__ v2f pk_fma_lo(v2f a, v2f s, v2f c) {
    v2f d; asm("v_pk_fma_f32 %0, %1, %2, %3 op_sel_hi:[1,0,1]"
               : "=v"(d) : "v"(a), "v"(s), "v"(c)); return d;
}
// d = a * broadcast(src1.hi) + c
__device__ __forceinline__ v2f pk_fma_hi(v2f a, v2f s, v2f c) {
    v2f d; asm("v_pk_fma_f32 %0, %1, %2, %3 op_sel:[0,1,0] op_sel_hi:[1,1,1]"
               : "=v"(d) : "v"(a), "v"(s), "v"(c)); return d;
}
__device__ __forceinline__ v2f pk_exp(v2f t) {  // 2 HW exp2 into a pair
    v2f e; e.x = fast_exp2(t.x); e.y = fast_exp2(t.y); return e;
}
__device__ __forceinline__ v2f lo2(float4 w) { return pk2(w.x, w.y); }
__device__ __forceinline__ v2f hi2(float4 w) { return pk2(w.z, w.w); }

__global__ void weff_kernel(const float* __restrict__ W0, const int* __restrict__ I0,
                            const float* __restrict__ W1, const int* __restrict__ I1,
                            const float* __restrict__ W2, const int* __restrict__ I2,
                            float* __restrict__ ws) {
    int tid = blockIdx.x * blockDim.x + threadIdx.x;   // 0 .. 163839
    const float* W; const int* I; float* out; int outd; int e;
    if (tid < 65536)        { W = W0; I = I0; out = ws;          outd = 256; e = tid; }
    else if (tid < 131072)  { W = W1; I = I1; out = ws + 65536;  outd = 256; e = tid - 65536; }
    else if (tid < 163840)  { W = W2; I = I2; out = ws + 131072; outd = 128; e = tid - 131072; }
    else return;
    int o = e >> 8;       // out index (in-dim always 256)
    int i = e & 255;      // in index
    float w = W[e];       // coalesced (e = o*256 + i)
    int idx = I[e];
    // branchless atoms: [id, sin, tanh, square]
    float sn = __builtin_amdgcn_sinf(w * INV2PI);
    float th = 1.0f - 2.0f * fast_rcp(fast_exp2(w * SC) + 1.0f);
    float sq = w * w;
    float v = (idx == 1) ? sn : (idx == 2) ? th : (idx == 3) ? sq : w;
    // packed store: [i/4][o][i%4] -> main loop reads float4 of 4 K-values
    out[(i >> 2) * (outd * 4) + o * 4 + (i & 3)] = v;
}

// num/den of sum_{k=0..3} 1/B_k over 4 i-values, one row-pair packed.
// B = exp2(t-8) + 2^-8 = 2^-8 * (e^{2z}+1); shift folds into the t-fma.
struct ND { v2f n, d; };
__device__ __forceinline__ ND tree4(float4 pa, float4 pb, float4 w, v2f m8, v2f c8) {
    v2f h0 = pk2(pa.x, pa.y), h1 = pk2(pa.z, pa.w);
    v2f h2 = pk2(pb.x, pb.y), h3 = pk2(pb.z, pb.w);
    v2f wxy = lo2(w), wzw = hi2(w);
    v2f B0 = pk_add(pk_exp(pk_fma_lo(h0, wxy, m8)), c8);
    v2f B1 = pk_add(pk_exp(pk_fma_hi(h1, wxy, m8)), c8);
    v2f B2 = pk_add(pk_exp(pk_fma_lo(h2, wzw, m8)), c8);
    v2f B3 = pk_add(pk_exp(pk_fma_hi(h3, wzw, m8)), c8);
    v2f S1 = pk_add(B0, B1), P1 = pk_mul(B0, B1);
    v2f S2 = pk_add(B2, B3), P2 = pk_mul(B2, B3);
    ND r;
    r.n = pk_fma(S2, P1, pk_mul(S1, P2));
    r.d = pk_mul(P1, P2);
    return r;
}

// merge two 4-trees (16 sigma-terms, one row-pair) with ONE rcp per row.
__device__ __forceinline__ v2f sig8_acc(ND a, ND b, v2f acc) {
    v2f num = pk_fma(b.n, a.d, pk_mul(a.n, b.d));
    v2f den = pk_mul(a.d, b.d);
    v2f rd;  rd.x = fast_rcp(den.x); rd.y = fast_rcp(den.y);
    return pk_fma(num, rd, acc);
}

__global__ __launch_bounds__(512, 4) void mlp_kernel(
    const float* __restrict__ x,  const float* __restrict__ b0,
    const float* __restrict__ b1, const float* __restrict__ b2,
    const float* __restrict__ ws, float* __restrict__ out) {
    const float4* We0 = (const float4*)ws;             // [64][256] packed [ic][o][4]
    const float4* We1 = (const float4*)(ws + 65536);   // [64][256]
    const float4* We2 = (const float4*)(ws + 131072);  // [64][128]

    __shared__ __align__(16) v2f hA0[256];      // pair0: rows (row0, row0+1)
    __shared__ __align__(16) v2f hA1[256];      // pair1: rows (row0+2, row0+3)
    __shared__ __align__(16) v2f hB0[256];
    __shared__ __align__(16) v2f hB1[256];
    __shared__ __align__(16) v2f partA[512];    // split-K partials, pair 0
    __shared__ __align__(16) v2f partB[512];    // pair 1

    const int t = threadIdx.x;     // 0..511
    const int g = t >> 8;          // K-group (wave-uniform)
    const int o = t & 255;         // neuron
    const int row0 = blockIdx.x * 4;

    const v2f m8 = pk2(-8.0f, -8.0f);
    const v2f c8 = pk2(C8, C8);

    // stage 4 input rows: pair p lane l holds row row0+2p+l (l == g here).
    {
        float xv = x[(row0 + g) * 256 + o] * SC;
        xv = fminf(fmaxf(xv, -HS_CLAMP), HS_CLAMP);
        ((float*)&hA0[o])[g] = xv;
        float xw = x[(row0 + 2 + g) * 256 + o] * SC;
        xw = fminf(fmaxf(xw, -HS_CLAMP), HS_CLAMP);
        ((float*)&hA1[o])[g] = xw;
    }
    __syncthreads();

    // ---------------- layer 0: hA* -> hB* ----------------
    {
        const float bias = b0[o];
        v2f acc0 = pk2(0.f, 0.f), acc1 = pk2(0.f, 0.f);
#pragma unroll 2
        for (int icc = 0; icc < 32; icc += 2) {
            int ic = g * 32 + icc;
            float4 w0 = We0[ic * 256 + o];
            float4 w1 = We0[(ic + 1) * 256 + o];
            const float4* hp0 = (const float4*)(hA0 + ic * 4);
            const float4* hp1 = (const float4*)(hA1 + ic * 4);
            ND r0 = tree4(hp0[0], hp0[1], w0, m8, c8);
            ND r1 = tree4(hp0[2], hp0[3], w1, m8, c8);
            acc0 = sig8_acc(r0, r1, acc0);
            ND r2 = tree4(hp1[0], hp1[1], w0, m8, c8);   // independent chain
            ND r3 = tree4(hp1[2], hp1[3], w1, m8, c8);
            acc1 = sig8_acc(r2, r3, acc1);
        }
        partA[g * 256 + o] = acc0;
        partB[g * 256 + o] = acc1;
        __syncthreads();
        float s0 = ((const float*)(partA + o))[g] + ((const float*)(partA + 256 + o))[g];
        float h0 = (256.0f - 0.0078125f * s0 + bias) * SC;   // 2^-7 undoes B-scale x2
        h0 = fminf(fmaxf(h0, -HS_CLAMP), HS_CLAMP);
        ((float*)&hB0[o])[g] = h0;
        float s1 = ((const float*)(partB + o))[g] + ((const float*)(partB + 256 + o))[g];
        float h1 = (256.0f - 0.0078125f * s1 + bias) * SC;
        h1 = fminf(fmaxf(h1, -HS_CLAMP), HS_CLAMP);
        ((float*)&hB1[o])[g] = h1;
        __syncthreads();
    }

    // ---------------- layer 1: hB* -> hA* ----------------
    {
        const float bias = b1[o];
        v2f acc0 = pk2(0.f, 0.f), acc1 = pk2(0.f, 0.f);
#pragma unroll 2
        for (int icc = 0; icc < 32; icc += 2) {
            int ic = g * 32 + icc;
            float4 w0 = We1[ic * 256 + o];
            float4 w1 = We1[(ic + 1) * 256 + o];
            const float4* hp0 = (const float4*)(hB0 + ic * 4);
            const float4* hp1 = (const float4*)(hB1 + ic * 4);
            ND r0 = tree4(hp0[0], hp0[1], w0, m8, c8);
            ND r1 = tree4(hp0[2], hp0[3], w1, m8, c8);
            acc0 = sig8_acc(r0, r1, acc0);
            ND r2 = tree4(hp1[0], hp1[1], w0, m8, c8);
            ND r3 = tree4(hp1[2], hp1[3], w1, m8, c8);
            acc1 = sig8_acc(r2, r3, acc1);
        }
        partA[g * 256 + o] = acc0;
        partB[g * 256 + o] = acc1;
        __syncthreads();
        float s0 = ((const float*)(partA + o))[g] + ((const float*)(partA + 256 + o))[g];
        float h0 = (256.0f - 0.0078125f * s0 + bias) * SC;
        h0 = fminf(fmaxf(h0, -HS_CLAMP), HS_CLAMP);
        ((float*)&hA0[o])[g] = h0;
        float s1 = ((const float*)(partB + o))[g] + ((const float*)(partB + 256 + o))[g];
        float h1 = (256.0f - 0.0078125f * s1 + bias) * SC;
        h1 = fminf(fmaxf(h1, -HS_CLAMP), HS_CLAMP);
        ((float*)&hB1[o])[g] = h1;   // NOTE: pair1 output kept in hB1? no -- see below
        __syncthreads();
    }

    // ---------------- layer 2: (hA0, hB1-as-pair1) -> out ------------------
    // pair0 final activations are in hA0; pair1's were written to hB1 above
    // (deliberate: hA1 and hB1 are both free post-layer-1; using hB1 avoids
    // a WAR hazard on hA1 being read in the same phase).
    {
        const int o2 = t & 127;
        const int q  = t >> 7;     // K-quarter 0..3
        v2f acc0 = pk2(0.f, 0.f), acc1 = pk2(0.f, 0.f);
#pragma unroll 4
        for (int icc = 0; icc < 16; icc++) {
            int ic = q * 16 + icc;
            float4 w = We2[ic * 128 + o2];
            const float4* hp0 = (const float4*)(hA0 + ic * 4);
            const float4* hp1 = (const float4*)(hB1 + ic * 4);
            float4 pa = hp0[0], pb = hp0[1];
            float4 qa = hp1[0], qb = hp1[1];
            v2f wxy = lo2(w), wzw = hi2(w);
            acc0 = pk_fma_lo(pk2(pa.x, pa.y), wxy, acc0);
            acc0 = pk_fma_hi(pk2(pa.z, pa.w), wxy, acc0);
            acc0 = pk_fma_lo(pk2(pb.x, pb.y), wzw, acc0);
            acc0 = pk_fma_hi(pk2(pb.z, pb.w), wzw, acc0);
            acc1 = pk_fma_lo(pk2(qa.x, qa.y), wxy, acc1);
            acc1 = pk_fma_hi(pk2(qa.z, qa.w), wxy, acc1);
            acc1 = pk_fma_lo(pk2(qb.x, qb.y), wzw, acc1);
            acc1 = pk_fma_hi(pk2(qb.z, qb.w), wzw, acc1);
        }
        partA[q * 128 + o2] = acc0;
        partB[q * 128 + o2] = acc1;
        __syncthreads();
        // 512 outputs (4 rows x 128), one per thread.
        const int r  = t >> 7;        // 0..3 -> row row0 + r
        const int oo = t & 127;
        const v2f* prt = (r & 2) ? partB : partA;
        const int  ln  = r & 1;
        float s = ((const float*)(prt + oo))[ln]
                + ((const float*)(prt + 128 + oo))[ln]
                + ((const float*)(prt + 256 + oo))[ln]
                + ((const float*)(prt + 384 + oo))[ln];
        out[(row0 + r) * 128 + oo] = s * INV + b2[oo];  // undo SC prescale
    }
}

extern "C" void kernel_launch(void* const* d_in, const int* in_sizes, int n_in,
                              void* d_out, int out_size, void* d_ws, size_t ws_size,
                              hipStream_t stream) {
    const float* x  = (const float*)d_in[0];
    const float* W0 = (const float*)d_in[1];
    const float* b0 = (const float*)d_in[2];
    const int*   I0 = (const int*)  d_in[3];
    const float* W1 = (const float*)d_in[4];
    const float* b1 = (const float*)d_in[5];
    const int*   I1 = (const int*)  d_in[6];
    const float* W2 = (const float*)d_in[7];
    const float* b2 = (const float*)d_in[8];
    const int*   I2 = (const int*)  d_in[9];
    float* ws  = (float*)d_ws;    // 163840 floats = 655360 B
    float* out = (float*)d_out;

    weff_kernel<<<640, 256, 0, stream>>>(W0, I0, W1, I1, W2, I2, ws);
    mlp_kernel<<<512, 512, 0, stream>>>(x, b0, b1, b2, ws, out);
}